// Round 1
// baseline (21567.209 us; speedup 1.0000x reference)
//
#include <hip/hip_runtime.h>
#include <hip/hip_cooperative_groups.h>

namespace cg = cooperative_groups;

typedef __attribute__((ext_vector_type(8))) short short8b;
typedef __attribute__((ext_vector_type(4))) float f32x4;

#define B_   32
#define T_   512
#define I_   1024
#define H_   1024
#define K_   2048          // I + H
#define NB   256           // blocks (1 per CU), each owns HS columns of H
#define HS   4             // H columns per block -> 16 gate columns
#define NTHR 128           // 2 waves: wave m handles batches m*16..m*16+15
#define HLAST (B_ * H_)
#define TBH ((long)T_ * B_ * H_)

__device__ __forceinline__ unsigned short f2bf(float f) {
  union { float f; unsigned u; } c; c.f = f;
  unsigned r = (c.u + 0x7FFFu + ((c.u >> 16) & 1u)) >> 16;  // RNE
  return (unsigned short)r;
}

__device__ __forceinline__ float sig_(float x)  { return 1.0f / (1.0f + __expf(-x)); }
__device__ __forceinline__ float tanh_(float x) { return 1.0f - 2.0f / (__expf(2.0f * x) + 1.0f); }

// x [B][T][I] f32  ->  xb [T][B][I] bf16 (step-t slab contiguous)
__global__ void convert_x_kernel(const float* __restrict__ x, unsigned short* __restrict__ xb) {
  long vid = (long)blockIdx.x * blockDim.x + threadIdx.x;
  long o = vid * 4;
  if (o >= (long)T_ * B_ * I_) return;
  int i  = (int)(o & (I_ - 1));
  long bt = o >> 10;
  int b  = (int)(bt & (B_ - 1));
  int t  = (int)(bt >> 5);
  float4 v = *reinterpret_cast<const float4*>(x + (((long)b * T_ + t) << 10) + i);
  ushort4 pk;
  pk.x = f2bf(v.x); pk.y = f2bf(v.y); pk.z = f2bf(v.z); pk.w = f2bf(v.w);
  *reinterpret_cast<ushort4*>(xb + o) = pk;
}

// Persistent cooperative LSTM kernel. One grid.sync() per timestep.
// Block bid owns H columns j0..j0+3 => 16 gate columns (f,i,o,g) staged in LDS as bf16.
// LDS layout: col n (n = gate*4+cj) at byte n*4096; element k at byte (2k)^((n&7)<<4)
// (XOR swizzle keeps ds_read_b128 B-fragments conflict-free without padding).
template <bool XBF16>
__global__ void lstm_kernel(const unsigned short* __restrict__ xb,
                            const float* __restrict__ xf,
                            const float* __restrict__ Wf, const float* __restrict__ Wi,
                            const float* __restrict__ Wo, const float* __restrict__ Wc,
                            const float* __restrict__ bfp, const float* __restrict__ bip,
                            const float* __restrict__ bop, const float* __restrict__ bcp,
                            float* __restrict__ out, unsigned short* __restrict__ hbuf)
{
  __shared__ unsigned short Wl[16 * 2048];  // exactly 64 KiB
  const int tid = threadIdx.x;
  const int bid = blockIdx.x;
  const int j0  = bid * HS;

  // ---- one-time: stage weight stripe to LDS (f32 -> bf16) ----
  {
    const float* Wg[4] = {Wf, Wi, Wo, Wc};
    for (int g = 0; g < 4; ++g) {
      const float* Wp = Wg[g] + j0;
      for (int k = tid; k < K_; k += NTHR) {
        float4 w = *reinterpret_cast<const float4*>(Wp + (long)k * H_);
        float wv[4] = {w.x, w.y, w.z, w.w};
        #pragma unroll
        for (int cj = 0; cj < 4; ++cj) {
          int n = g * 4 + cj;
          int byteoff = n * 4096 + ((2 * k) ^ ((n & 7) << 4));
          *reinterpret_cast<unsigned short*>(reinterpret_cast<char*>(Wl) + byteoff) = f2bf(wv[cj]);
        }
      }
    }
  }
  __syncthreads();

  const int lane = tid & 63;
  const int m    = tid >> 6;            // wave = M-tile (batches m*16..+15)
  const int lr   = lane & 15;
  const int lg   = lane >> 4;
  const int b    = m * 16 + lr;         // batch row this lane feeds into A-fragment
  const int cj   = lane & 3;            // H-column (within block) this lane gates
  const int gb0  = m * 16 + lg * 4;     // first batch row this lane gates

  const float bias_f = bfp[j0 + cj];
  const float bias_i = bip[j0 + cj];
  const float bias_o = bop[j0 + cj];
  const float bias_g = bcp[j0 + cj];

  float creg[4] = {0.f, 0.f, 0.f, 0.f};  // c state lives in registers all T steps

  unsigned short* hb0 = hbuf;
  unsigned short* hb1 = hbuf + B_ * H_;

  const char* WlB   = reinterpret_cast<const char*>(Wl);
  const int colbase = lr * 4096;
  const int swz     = (lr & 7) << 4;

  cg::grid_group grid = cg::this_grid();

  for (int t = 0; t < T_; ++t) {
    const unsigned short* hcur = (t & 1) ? hb1 : hb0;
    unsigned short*       hnxt = (t & 1) ? hb0 : hb1;

    f32x4 acc = {0.f, 0.f, 0.f, 0.f};

    // ---- x part: k in [0,1024) ----
    if (XBF16) {
      const unsigned short* aptr = xb + (((long)(t * B_ + b)) << 10) + lg * 8;
      #pragma unroll
      for (int it = 0; it < 32; ++it) {
        short8b a  = *reinterpret_cast<const short8b*>(aptr + it * 32);
        short8b bb = *reinterpret_cast<const short8b*>(WlB + colbase + ((it * 64 + lg * 16) ^ swz));
        acc = __builtin_amdgcn_mfma_f32_16x16x32_bf16(a, bb, acc, 0, 0, 0);
      }
    } else {
      const float* aptr = xf + (((long)b * T_ + t) << 10) + lg * 8;
      #pragma unroll
      for (int it = 0; it < 32; ++it) {
        float4 v0 = *reinterpret_cast<const float4*>(aptr + it * 32);
        float4 v1 = *reinterpret_cast<const float4*>(aptr + it * 32 + 4);
        short8b a;
        a[0] = (short)f2bf(v0.x); a[1] = (short)f2bf(v0.y);
        a[2] = (short)f2bf(v0.z); a[3] = (short)f2bf(v0.w);
        a[4] = (short)f2bf(v1.x); a[5] = (short)f2bf(v1.y);
        a[6] = (short)f2bf(v1.z); a[7] = (short)f2bf(v1.w);
        short8b bb = *reinterpret_cast<const short8b*>(WlB + colbase + ((it * 64 + lg * 16) ^ swz));
        acc = __builtin_amdgcn_mfma_f32_16x16x32_bf16(a, bb, acc, 0, 0, 0);
      }
    }

    // ---- h part: k in [1024,2048) ----
    {
      const unsigned short* aptr = hcur + (b << 10) + lg * 8;
      #pragma unroll
      for (int it = 0; it < 32; ++it) {
        short8b a  = *reinterpret_cast<const short8b*>(aptr + it * 32);
        short8b bb = *reinterpret_cast<const short8b*>(WlB + colbase + ((2048 + it * 64 + lg * 16) ^ swz));
        acc = __builtin_amdgcn_mfma_f32_16x16x32_bf16(a, bb, acc, 0, 0, 0);
      }
    }

    // ---- gate redistribution: D[row = lg*4+r][col = lr]; lane wants cols g*4+cj ----
    float gate[4][4];
    #pragma unroll
    for (int g = 0; g < 4; ++g) {
      const int src = lg * 16 + g * 4 + cj;
      #pragma unroll
      for (int r = 0; r < 4; ++r) gate[g][r] = __shfl(acc[r], src, 64);
    }

    float hv[4];
    #pragma unroll
    for (int r = 0; r < 4; ++r) {
      float fg = sig_(gate[0][r] + bias_f);
      float ig = sig_(gate[1][r] + bias_i);
      float og = sig_(gate[2][r] + bias_o);
      float gg = tanh_(gate[3][r] + bias_g);
      float c  = fg * creg[r] + ig * gg;
      creg[r]  = c;
      hv[r]    = og * tanh_(c);
    }

    if ((lane & 12) == 0) {  // lanes lr<4 are the unique writers (4x lane redundancy)
      #pragma unroll
      for (int r = 0; r < 4; ++r) {
        const int row  = gb0 + r;
        const int colj = j0 + cj;
        const long oh  = (long)(t * B_ + row) * H_ + colj;
        out[HLAST + oh]        = hv[r];
        out[HLAST + TBH + oh]  = creg[r];
        hnxt[row * H_ + colj]  = f2bf(hv[r]);
        if (t == T_ - 1) out[(long)row * H_ + colj] = hv[r];
      }
    }

    grid.sync();   // publishes h[t] to all blocks for step t+1
  }
}

extern "C" void kernel_launch(void* const* d_in, const int* in_sizes, int n_in,
                              void* d_out, int out_size, void* d_ws, size_t ws_size,
                              hipStream_t stream) {
  const float* x   = (const float*)d_in[0];
  const float* Wf  = (const float*)d_in[1];
  const float* bf_ = (const float*)d_in[2];
  const float* Wi  = (const float*)d_in[3];
  const float* bi_ = (const float*)d_in[4];
  const float* Wo  = (const float*)d_in[5];
  const float* bo_ = (const float*)d_in[6];
  const float* Wc  = (const float*)d_in[7];
  const float* bc_ = (const float*)d_in[8];
  float* out = (float*)d_out;

  const size_t xb_bytes   = (size_t)T_ * B_ * I_ * 2;  // 32 MiB
  const size_t hbuf_bytes = (size_t)2 * B_ * H_ * 2;   // 128 KiB
  const bool use_xbf16 = ws_size >= xb_bytes + hbuf_bytes;

  unsigned short* xb;
  unsigned short* hbuf;
  if (use_xbf16) {
    xb   = (unsigned short*)d_ws;
    hbuf = (unsigned short*)((char*)d_ws + xb_bytes);
  } else {
    xb   = (unsigned short*)d_ws;   // unused in this path
    hbuf = (unsigned short*)d_ws;
  }

  (void)hipMemsetAsync(hbuf, 0, hbuf_bytes, stream);  // h0 = 0 (both buffers)

  if (use_xbf16) {
    const int total_vec = T_ * B_ * I_ / 4;
    convert_x_kernel<<<dim3(total_vec / 256), dim3(256), 0, stream>>>(x, xb);
  }

  void* kfn = use_xbf16 ? (void*)lstm_kernel<true> : (void*)lstm_kernel<false>;
  void* args[] = { &xb, &x, &Wf, &Wi, &Wo, &Wc, &bf_, &bi_, &bo_, &bc_, &out, &hbuf };
  (void)hipLaunchCooperativeKernel(kfn, dim3(NB), dim3(NTHR), args, 0, stream);
}

// Round 4
// 6337.503 us; speedup vs baseline: 3.4031x; 3.4031x over previous
//
#include <hip/hip_runtime.h>

typedef __attribute__((ext_vector_type(8))) short short8b;
typedef __attribute__((ext_vector_type(4))) float f32x4;

#define B_   32
#define T_   512
#define I_   1024
#define H_   1024
#define K_   2048          // I + H
#define NB   256           // blocks per step-kernel; block owns 4 H-cols (16 gate cols)
#define NTHR 128           // 2 waves: wave m handles batch rows m*16..m*16+15
#define BH   (B_ * H_)
#define HLAST (B_ * H_)
#define TBH ((long)T_ * B_ * H_)

__device__ __forceinline__ unsigned short f2bf(float f) {
  union { float f; unsigned u; } c; c.f = f;
  unsigned r = (c.u + 0x7FFFu + ((c.u >> 16) & 1u)) >> 16;  // RNE
  return (unsigned short)r;
}

__device__ __forceinline__ float sig_(float x)  { return 1.0f / (1.0f + __expf(-x)); }
__device__ __forceinline__ float tanh_(float x) { return 1.0f - 2.0f / (__expf(2.0f * x) + 1.0f); }

// x [B][T][I] f32  ->  xb [T][B][I] bf16 (step-t slab contiguous)
__global__ void convert_x_kernel(const float* __restrict__ x, unsigned short* __restrict__ xb) {
  long vid = (long)blockIdx.x * blockDim.x + threadIdx.x;
  long o = vid * 4;
  if (o >= (long)T_ * B_ * I_) return;
  int i  = (int)(o & (I_ - 1));
  long bt = o >> 10;
  int b  = (int)(bt & (B_ - 1));
  int t  = (int)(bt >> 5);
  float4 v = *reinterpret_cast<const float4*>(x + (((long)b * T_ + t) << 10) + i);
  ushort4 pk;
  pk.x = f2bf(v.x); pk.y = f2bf(v.y); pk.z = f2bf(v.z); pk.w = f2bf(v.w);
  *reinterpret_cast<ushort4*>(xb + o) = pk;
}

// Pack W into MFMA B-fragment layout, bf16:
// frag index v = (bid*64 + it)*64 + lane  ->  8 bf16 at Wp[v*8 .. v*8+8)
// frag(v) element e = Wg[g][(k0+e)*H + bid*4 + cjb], where n=lane&15, g=n>>2,
// cjb=n&3, lg=lane>>4, k0 = it*32 + lg*8  (k in [0,2048): x rows then h rows).
// Step-kernel reads are then fully coalesced (consecutive lanes = consecutive 16B).
__global__ void pack_w_kernel(const float* __restrict__ Wf, const float* __restrict__ Wi,
                              const float* __restrict__ Wo, const float* __restrict__ Wc,
                              unsigned short* __restrict__ Wp) {
  int v = blockIdx.x * blockDim.x + threadIdx.x;   // [0, 256*64*64)
  int lane = v & 63;
  int it   = (v >> 6) & 63;
  int bid  = v >> 12;
  int n   = lane & 15;
  int lg  = lane >> 4;
  int g   = n >> 2;
  int col = bid * 4 + (n & 3);
  int k0  = it * 32 + lg * 8;
  const float* Wg = (g == 0) ? Wf : (g == 1) ? Wi : (g == 2) ? Wo : Wc;
  short8b fr;
  #pragma unroll
  for (int e = 0; e < 8; ++e)
    fr[e] = (short)f2bf(Wg[(size_t)(k0 + e) * H_ + col]);
  *reinterpret_cast<short8b*>(Wp + (size_t)v * 8) = fr;
}

// One timestep. No cross-block communication inside the kernel; the stream/graph
// serializes steps and the CP handles inter-dispatch coherence.
// Block bid owns H-cols [bid*4, bid*4+4) => 16 gate cols. c state round-trips
// through the c_states output slab (each block reads exactly the cells it wrote
// at step t-1 — race-free). h ping-pongs through a bf16 ws buffer.
template <int MODE>   // 0: packed bf16 W + bf16 x ; 2: gather raw f32 (ws-too-small fallback)
__global__ void lstm_step_kernel(int t,
    const unsigned short* __restrict__ xb, const unsigned short* __restrict__ Wp,
    const float* __restrict__ xf,
    const float* __restrict__ Wf, const float* __restrict__ Wi,
    const float* __restrict__ Wo, const float* __restrict__ Wc,
    const float* __restrict__ bfp, const float* __restrict__ bip,
    const float* __restrict__ bop, const float* __restrict__ bcp,
    float* __restrict__ out, unsigned short* __restrict__ hbuf)
{
  const int tid  = threadIdx.x;
  const int bid  = blockIdx.x;
  const int lane = tid & 63;
  const int m    = tid >> 6;
  const int lr   = lane & 15;
  const int lg   = lane >> 4;
  const int b    = m * 16 + lr;     // batch row in A-fragment
  const int cj   = lane & 3;        // H-col (within block) this lane gates
  const int j0   = bid * 4;
  const int gb0  = m * 16 + lg * 4;

  const unsigned short* hcur = hbuf + (t & 1) * BH;

  f32x4 a0 = {0.f, 0.f, 0.f, 0.f};
  f32x4 a1 = {0.f, 0.f, 0.f, 0.f};

  if (MODE == 0) {
    const unsigned short* ax = xb + (((long)t * B_ + b) << 10) + lg * 8;
    const unsigned short* ah = hcur + (b << 10) + lg * 8;
    const unsigned short* wp = Wp + (size_t)bid * 32768 + lane * 8;  // frag(bid,0,lane)
    #pragma unroll
    for (int it = 0; it < 32; ++it) {   // x part: k in [0,1024)
      short8b a  = *reinterpret_cast<const short8b*>(ax + it * 32);
      short8b bb = *reinterpret_cast<const short8b*>(wp + it * 512);
      if (it & 1) a1 = __builtin_amdgcn_mfma_f32_16x16x32_bf16(a, bb, a1, 0, 0, 0);
      else        a0 = __builtin_amdgcn_mfma_f32_16x16x32_bf16(a, bb, a0, 0, 0, 0);
    }
    #pragma unroll
    for (int it = 0; it < 32; ++it) {   // h part: k in [1024,2048)
      short8b a  = *reinterpret_cast<const short8b*>(ah + it * 32);
      short8b bb = *reinterpret_cast<const short8b*>(wp + (32 + it) * 512);
      if (it & 1) a1 = __builtin_amdgcn_mfma_f32_16x16x32_bf16(a, bb, a1, 0, 0, 0);
      else        a0 = __builtin_amdgcn_mfma_f32_16x16x32_bf16(a, bb, a0, 0, 0, 0);
    }
  } else {
    // fallback: gather everything from the raw f32 inputs each step (slow, correct)
    const int g    = lr >> 2;
    const int colg = j0 + (lr & 3);
    const float* Wg = (g == 0) ? Wf : (g == 1) ? Wi : (g == 2) ? Wo : Wc;
    const float* axf = xf + ((long)b * T_ + t) * I_ + lg * 8;
    const unsigned short* ah = hcur + (b << 10) + lg * 8;
    #pragma unroll 4
    for (int it = 0; it < 32; ++it) {
      const int k0 = it * 32 + lg * 8;
      short8b a, bb;
      #pragma unroll
      for (int e = 0; e < 8; ++e) {
        a[e]  = (short)f2bf(axf[it * 32 + e]);
        bb[e] = (short)f2bf(Wg[(size_t)(k0 + e) * H_ + colg]);
      }
      if (it & 1) a1 = __builtin_amdgcn_mfma_f32_16x16x32_bf16(a, bb, a1, 0, 0, 0);
      else        a0 = __builtin_amdgcn_mfma_f32_16x16x32_bf16(a, bb, a0, 0, 0, 0);
    }
    #pragma unroll 4
    for (int it = 0; it < 32; ++it) {
      const int k0 = 1024 + it * 32 + lg * 8;
      short8b a = *reinterpret_cast<const short8b*>(ah + it * 32);
      short8b bb;
      #pragma unroll
      for (int e = 0; e < 8; ++e)
        bb[e] = (short)f2bf(Wg[(size_t)(k0 + e) * H_ + colg]);
      if (it & 1) a1 = __builtin_amdgcn_mfma_f32_16x16x32_bf16(a, bb, a1, 0, 0, 0);
      else        a0 = __builtin_amdgcn_mfma_f32_16x16x32_bf16(a, bb, a0, 0, 0, 0);
    }
  }
  f32x4 acc = a0 + a1;

  // gate redistribution: D[row=lg*4+r][col=lr]; this lane wants cols g*4+cj
  float gate[4][4];
  #pragma unroll
  for (int g = 0; g < 4; ++g) {
    const int src = lg * 16 + g * 4 + cj;
    #pragma unroll
    for (int r = 0; r < 4; ++r) gate[g][r] = __shfl(acc[r], src, 64);
  }

  if ((lane & 12) == 0) {   // unique writer lanes (lr < 4)
    const int col = j0 + cj;
    const float bias_f = bfp[col];
    const float bias_i = bip[col];
    const float bias_o = bop[col];
    const float bias_g = bcp[col];
    #pragma unroll
    for (int r = 0; r < 4; ++r) {
      const int row = gb0 + r;
      float cprev = (t == 0) ? 0.f
                  : out[HLAST + TBH + (long)((t - 1) * B_ + row) * H_ + col];
      float fg = sig_(gate[0][r] + bias_f);
      float ig = sig_(gate[1][r] + bias_i);
      float og = sig_(gate[2][r] + bias_o);
      float gg = tanh_(gate[3][r] + bias_g);
      float c  = fg * cprev + ig * gg;
      float hv = og * tanh_(c);
      const long oh = (long)(t * B_ + row) * H_ + col;
      out[HLAST + oh]       = hv;
      out[HLAST + TBH + oh] = c;
      hbuf[((t + 1) & 1) * BH + row * H_ + col] = f2bf(hv);
      if (t == T_ - 1) out[(long)row * H_ + col] = hv;
    }
  }
}

extern "C" void kernel_launch(void* const* d_in, const int* in_sizes, int n_in,
                              void* d_out, int out_size, void* d_ws, size_t ws_size,
                              hipStream_t stream) {
  const float* x   = (const float*)d_in[0];
  const float* Wf  = (const float*)d_in[1];
  const float* bf_ = (const float*)d_in[2];
  const float* Wi  = (const float*)d_in[3];
  const float* bi_ = (const float*)d_in[4];
  const float* Wo  = (const float*)d_in[5];
  const float* bo_ = (const float*)d_in[6];
  const float* Wc  = (const float*)d_in[7];
  const float* bc_ = (const float*)d_in[8];
  float* out = (float*)d_out;

  const size_t xb_bytes = (size_t)T_ * B_ * I_ * 2;        // 32 MiB
  const size_t wp_bytes = (size_t)NB * 64 * 64 * 16;       // 16 MiB
  const size_t hb_bytes = (size_t)2 * BH * 2;              // 128 KiB
  const bool fast = ws_size >= xb_bytes + wp_bytes + hb_bytes;

  unsigned short* xb;
  unsigned short* Wp;
  unsigned short* hbuf;
  if (fast) {
    xb   = (unsigned short*)d_ws;
    Wp   = (unsigned short*)((char*)d_ws + xb_bytes);
    hbuf = (unsigned short*)((char*)d_ws + xb_bytes + wp_bytes);
  } else {
    xb = Wp = nullptr;
    hbuf = (unsigned short*)d_ws;
  }

  // h0 = 0 (zero buf0; buf1 is fully written at t=0 before t=1 reads it).
  // Must run every call: step 511 writes hbuf[0], so replays need re-zeroing.
  (void)hipMemsetAsync(hbuf, 0, hb_bytes, stream);

  if (fast) {
    const int total_vec = T_ * B_ * I_ / 4;
    convert_x_kernel<<<dim3(total_vec / 256), dim3(256), 0, stream>>>(x, xb);
    pack_w_kernel<<<dim3(NB * 64 * 64 / 256), dim3(256), 0, stream>>>(Wf, Wi, Wo, Wc, Wp);
  }

  for (int t = 0; t < T_; ++t) {
    if (fast)
      lstm_step_kernel<0><<<dim3(NB), dim3(NTHR), 0, stream>>>(
          t, xb, Wp, x, Wf, Wi, Wo, Wc, bf_, bi_, bo_, bc_, out, hbuf);
    else
      lstm_step_kernel<2><<<dim3(NB), dim3(NTHR), 0, stream>>>(
          t, xb, Wp, x, Wf, Wi, Wo, Wc, bf_, bi_, bo_, bc_, out, hbuf);
  }
}

// Round 5
// 4441.328 us; speedup vs baseline: 4.8560x; 1.4269x over previous
//
#include <hip/hip_runtime.h>

typedef __attribute__((ext_vector_type(8))) short short8b;
typedef __attribute__((ext_vector_type(4))) float f32x4;

#define B_   32
#define T_   512
#define I_   1024
#define H_   1024
#define K_   2048          // I + H
#define NB   256           // blocks per step-kernel; block owns 4 H-cols (16 gate cols)
#define BH   (B_ * H_)
#define HLAST (B_ * H_)
#define TBH ((long)T_ * B_ * H_)

__device__ __forceinline__ unsigned short f2bf(float f) {
  union { float f; unsigned u; } c; c.f = f;
  unsigned r = (c.u + 0x7FFFu + ((c.u >> 16) & 1u)) >> 16;  // RNE
  return (unsigned short)r;
}

__device__ __forceinline__ float sig_(float x)  { return 1.0f / (1.0f + __expf(-x)); }
__device__ __forceinline__ float tanh_(float x) { return 1.0f - 2.0f / (__expf(2.0f * x) + 1.0f); }

// x [B][T][I] f32  ->  xb [T][B][I] bf16 (step-t slab contiguous)
__global__ void convert_x_kernel(const float* __restrict__ x, unsigned short* __restrict__ xb) {
  long vid = (long)blockIdx.x * blockDim.x + threadIdx.x;
  long o = vid * 4;
  if (o >= (long)T_ * B_ * I_) return;
  int i  = (int)(o & (I_ - 1));
  long bt = o >> 10;
  int b  = (int)(bt & (B_ - 1));
  int t  = (int)(bt >> 5);
  float4 v = *reinterpret_cast<const float4*>(x + (((long)b * T_ + t) << 10) + i);
  ushort4 pk;
  pk.x = f2bf(v.x); pk.y = f2bf(v.y); pk.z = f2bf(v.z); pk.w = f2bf(v.w);
  *reinterpret_cast<ushort4*>(xb + o) = pk;
}

// Pack W into MFMA B-fragment layout (bf16). frag v = (bid*64 + f)*64 + lane:
// element e = Wg[g][(f*32 + lg*8 + e)*H + bid*4 + cjb], n=lane&15, g=n>>2,
// cjb=n&3, lg=lane>>4. Step-kernel B reads become fully coalesced 16B/lane.
__global__ void pack_w_kernel(const float* __restrict__ Wf, const float* __restrict__ Wi,
                              const float* __restrict__ Wo, const float* __restrict__ Wc,
                              unsigned short* __restrict__ Wp) {
  int v = blockIdx.x * blockDim.x + threadIdx.x;   // [0, 256*64*64)
  int lane = v & 63;
  int f    = (v >> 6) & 63;
  int bid  = v >> 12;
  int n   = lane & 15;
  int lg  = lane >> 4;
  int g   = n >> 2;
  int col = bid * 4 + (n & 3);
  int k0  = f * 32 + lg * 8;
  const float* Wg = (g == 0) ? Wf : (g == 1) ? Wi : (g == 2) ? Wo : Wc;
  short8b fr;
  #pragma unroll
  for (int e = 0; e < 8; ++e)
    fr[e] = (short)f2bf(Wg[(size_t)(k0 + e) * H_ + col]);
  *reinterpret_cast<short8b*>(Wp + (size_t)v * 8) = fr;
}

// One timestep, 8 waves/block. Wave w: q = w>>1 (K-quarter), m = w&1 (M-half).
// Each wave: 16 A-frags + 16 B-frags prefetched, 16 MFMAs. LDS reduce over q.
// c state round-trips through the c_states output slab; h via bf16 ws ping-pong.
__global__ __launch_bounds__(512, 2)
void lstm_step8_kernel(int t,
    const unsigned short* __restrict__ xb, const unsigned short* __restrict__ Wp,
    const float* __restrict__ bfp, const float* __restrict__ bip,
    const float* __restrict__ bop, const float* __restrict__ bcp,
    float* __restrict__ out, unsigned short* __restrict__ hbuf)
{
  __shared__ f32x4 part[8][64];
  const int tid  = threadIdx.x;
  const int bid  = blockIdx.x;
  const int lane = tid & 63;
  const int w    = tid >> 6;
  const int m    = w & 1;
  const int q    = w >> 1;
  const int lr   = lane & 15;
  const int lg   = lane >> 4;
  const int b    = m * 16 + lr;     // batch row in A-fragment
  const int j0   = bid * 4;

  // ---- hoisted tail-phase loads (latency hides under GEMM) ----
  const int cj  = lane & 3;
  const int gb0 = m * 16 + lg * 4;
  const bool writer = (w < 2) && ((lane & 12) == 0);
  float cprev[4] = {0.f, 0.f, 0.f, 0.f};
  float bias_f = 0.f, bias_i = 0.f, bias_o = 0.f, bias_g = 0.f;
  if (writer) {
    const int col = j0 + cj;
    bias_f = bfp[col]; bias_i = bip[col]; bias_o = bop[col]; bias_g = bcp[col];
    if (t > 0) {
      #pragma unroll
      for (int r = 0; r < 4; ++r)
        cprev[r] = out[HLAST + TBH + (long)((t - 1) * B_ + (gb0 + r)) * H_ + (j0 + cj)];
    }
  }

  // ---- prefetch this wave's 16 A-frags + 16 B-frags, then MFMA burst ----
  const unsigned short* aA = (q < 2)
      ? xb + (((long)t * B_ + b) << 10) + (q * 16) * 32 + lg * 8
      : hbuf + (t & 1) * BH + (b << 10) + ((q - 2) * 16) * 32 + lg * 8;
  const unsigned short* wp = Wp + (size_t)bid * 32768 + (size_t)(q * 16) * 512 + lane * 8;

  short8b Af[16], Bf[16];
  #pragma unroll
  for (int i = 0; i < 16; ++i) Af[i] = *reinterpret_cast<const short8b*>(aA + i * 32);
  #pragma unroll
  for (int i = 0; i < 16; ++i) Bf[i] = *reinterpret_cast<const short8b*>(wp + i * 512);

  f32x4 a0 = {0.f, 0.f, 0.f, 0.f};
  f32x4 a1 = {0.f, 0.f, 0.f, 0.f};
  #pragma unroll
  for (int i = 0; i < 16; ++i) {
    if (i & 1) a1 = __builtin_amdgcn_mfma_f32_16x16x32_bf16(Af[i], Bf[i], a1, 0, 0, 0);
    else       a0 = __builtin_amdgcn_mfma_f32_16x16x32_bf16(Af[i], Bf[i], a0, 0, 0, 0);
  }

  part[w][lane] = a0 + a1;
  __syncthreads();

  if (w < 2) {
    f32x4 acc = part[m][lane] + part[2 + m][lane] + part[4 + m][lane] + part[6 + m][lane];

    // gate redistribution: D[row=lg*4+r][col=lr]; lane wants cols g*4+cj
    float gate[4][4];
    #pragma unroll
    for (int g = 0; g < 4; ++g) {
      const int src = lg * 16 + g * 4 + cj;
      #pragma unroll
      for (int r = 0; r < 4; ++r) gate[g][r] = __shfl(acc[r], src, 64);
    }

    if (writer) {
      const int col = j0 + cj;
      #pragma unroll
      for (int r = 0; r < 4; ++r) {
        const int row = gb0 + r;
        float fg = sig_(gate[0][r] + bias_f);
        float ig = sig_(gate[1][r] + bias_i);
        float og = sig_(gate[2][r] + bias_o);
        float gg = tanh_(gate[3][r] + bias_g);
        float c  = fg * cprev[r] + ig * gg;
        float hv = og * tanh_(c);
        const long oh = (long)(t * B_ + row) * H_ + col;
        out[HLAST + oh]       = hv;
        out[HLAST + TBH + oh] = c;
        hbuf[((t + 1) & 1) * BH + row * H_ + col] = f2bf(hv);
        if (t == T_ - 1) out[(long)row * H_ + col] = hv;
      }
    }
  }
}

// Fallback (ws too small): round-4 2-wave kernel gathering raw f32 each step.
__global__ void lstm_step_fallback_kernel(int t,
    const float* __restrict__ xf,
    const float* __restrict__ Wf, const float* __restrict__ Wi,
    const float* __restrict__ Wo, const float* __restrict__ Wc,
    const float* __restrict__ bfp, const float* __restrict__ bip,
    const float* __restrict__ bop, const float* __restrict__ bcp,
    float* __restrict__ out, unsigned short* __restrict__ hbuf)
{
  const int tid  = threadIdx.x;
  const int bid  = blockIdx.x;
  const int lane = tid & 63;
  const int m    = tid >> 6;
  const int lr   = lane & 15;
  const int lg   = lane >> 4;
  const int b    = m * 16 + lr;
  const int cj   = lane & 3;
  const int j0   = bid * 4;
  const int gb0  = m * 16 + lg * 4;

  const unsigned short* hcur = hbuf + (t & 1) * BH;
  f32x4 a0 = {0.f, 0.f, 0.f, 0.f};
  f32x4 a1 = {0.f, 0.f, 0.f, 0.f};

  const int g    = lr >> 2;
  const int colg = j0 + (lr & 3);
  const float* Wg = (g == 0) ? Wf : (g == 1) ? Wi : (g == 2) ? Wo : Wc;
  const float* axf = xf + ((long)b * T_ + t) * I_ + lg * 8;
  const unsigned short* ah = hcur + (b << 10) + lg * 8;
  #pragma unroll 4
  for (int it = 0; it < 32; ++it) {
    const int k0 = it * 32 + lg * 8;
    short8b a, bb;
    #pragma unroll
    for (int e = 0; e < 8; ++e) {
      a[e]  = (short)f2bf(axf[it * 32 + e]);
      bb[e] = (short)f2bf(Wg[(size_t)(k0 + e) * H_ + colg]);
    }
    if (it & 1) a1 = __builtin_amdgcn_mfma_f32_16x16x32_bf16(a, bb, a1, 0, 0, 0);
    else        a0 = __builtin_amdgcn_mfma_f32_16x16x32_bf16(a, bb, a0, 0, 0, 0);
  }
  #pragma unroll 4
  for (int it = 0; it < 32; ++it) {
    const int k0 = 1024 + it * 32 + lg * 8;
    short8b a = *reinterpret_cast<const short8b*>(ah + it * 32);
    short8b bb;
    #pragma unroll
    for (int e = 0; e < 8; ++e)
      bb[e] = (short)f2bf(Wg[(size_t)(k0 + e) * H_ + colg]);
    if (it & 1) a1 = __builtin_amdgcn_mfma_f32_16x16x32_bf16(a, bb, a1, 0, 0, 0);
    else        a0 = __builtin_amdgcn_mfma_f32_16x16x32_bf16(a, bb, a0, 0, 0, 0);
  }
  f32x4 acc = a0 + a1;

  float gate[4][4];
  #pragma unroll
  for (int gg = 0; gg < 4; ++gg) {
    const int src = lg * 16 + gg * 4 + cj;
    #pragma unroll
    for (int r = 0; r < 4; ++r) gate[gg][r] = __shfl(acc[r], src, 64);
  }

  if ((lane & 12) == 0) {
    const int col = j0 + cj;
    const float bias_f = bfp[col];
    const float bias_i = bip[col];
    const float bias_o = bop[col];
    const float bias_g = bcp[col];
    #pragma unroll
    for (int r = 0; r < 4; ++r) {
      const int row = gb0 + r;
      float cp = (t == 0) ? 0.f
               : out[HLAST + TBH + (long)((t - 1) * B_ + row) * H_ + col];
      float fg = sig_(gate[0][r] + bias_f);
      float ig = sig_(gate[1][r] + bias_i);
      float og = sig_(gate[2][r] + bias_o);
      float gv = tanh_(gate[3][r] + bias_g);
      float c  = fg * cp + ig * gv;
      float hv = og * tanh_(c);
      const long oh = (long)(t * B_ + row) * H_ + col;
      out[HLAST + oh]       = hv;
      out[HLAST + TBH + oh] = c;
      hbuf[((t + 1) & 1) * BH + row * H_ + col] = f2bf(hv);
      if (t == T_ - 1) out[(long)row * H_ + col] = hv;
    }
  }
}

extern "C" void kernel_launch(void* const* d_in, const int* in_sizes, int n_in,
                              void* d_out, int out_size, void* d_ws, size_t ws_size,
                              hipStream_t stream) {
  const float* x   = (const float*)d_in[0];
  const float* Wf  = (const float*)d_in[1];
  const float* bf_ = (const float*)d_in[2];
  const float* Wi  = (const float*)d_in[3];
  const float* bi_ = (const float*)d_in[4];
  const float* Wo  = (const float*)d_in[5];
  const float* bo_ = (const float*)d_in[6];
  const float* Wc  = (const float*)d_in[7];
  const float* bc_ = (const float*)d_in[8];
  float* out = (float*)d_out;

  const size_t xb_bytes = (size_t)T_ * B_ * I_ * 2;        // 32 MiB
  const size_t wp_bytes = (size_t)NB * 64 * 64 * 16;       // 16 MiB
  const size_t hb_bytes = (size_t)2 * BH * 2;              // 128 KiB
  const bool fast = ws_size >= xb_bytes + wp_bytes + hb_bytes;

  unsigned short* xb;
  unsigned short* Wp;
  unsigned short* hbuf;
  if (fast) {
    xb   = (unsigned short*)d_ws;
    Wp   = (unsigned short*)((char*)d_ws + xb_bytes);
    hbuf = (unsigned short*)((char*)d_ws + xb_bytes + wp_bytes);
  } else {
    xb = Wp = nullptr;
    hbuf = (unsigned short*)d_ws;
  }

  // h0 = 0 (zero buf0; buf1 is fully written at t=0 before t=1 reads it).
  // Must run every call: step 511 writes hbuf[0], so replays need re-zeroing.
  (void)hipMemsetAsync(hbuf, 0, hb_bytes, stream);

  if (fast) {
    const int total_vec = T_ * B_ * I_ / 4;
    convert_x_kernel<<<dim3(total_vec / 256), dim3(256), 0, stream>>>(x, xb);
    pack_w_kernel<<<dim3(NB * 64 * 64 / 256), dim3(256), 0, stream>>>(Wf, Wi, Wo, Wc, Wp);
    for (int t = 0; t < T_; ++t)
      lstm_step8_kernel<<<dim3(NB), dim3(512), 0, stream>>>(
          t, xb, Wp, bf_, bi_, bo_, bc_, out, hbuf);
  } else {
    for (int t = 0; t < T_; ++t)
      lstm_step_fallback_kernel<<<dim3(NB), dim3(128), 0, stream>>>(
          t, x, Wf, Wi, Wo, Wc, bf_, bi_, bo_, bc_, out, hbuf);
  }
}